// Round 1
// baseline (1780.830 us; speedup 1.0000x reference)
//
#include <hip/hip_runtime.h>
#include <hip/hip_bf16.h>
#include <cstddef>

// Problem constants (fixed-shape problem)
constexpr int B_ = 4, T_ = 4096, D_ = 512, K_ = 8192;
constexpr int N_ = B_ * T_;                 // 16384 rows
constexpr int SPLITS = 8;                   // K split across blocks: 8192/8 = 1024 per block
constexpr int KSPAN = K_ / SPLITS;          // 1024
constexpr int BM = 128;                     // rows per block
constexpr int BN = 128;                     // cols per n-chunk
constexpr int BK = 16;                      // d per stage

// -------------------- kernel 1: ehs[k] = 0.5 * ||embed[k]||^2 --------------------
__global__ __launch_bounds__(256) void ehs_kernel(const float* __restrict__ embed,
                                                  float* __restrict__ ehs) {
  int gwave = (blockIdx.x * 256 + threadIdx.x) >> 6;
  int lane = threadIdx.x & 63;
  if (gwave >= K_) return;
  const float4* e4 = (const float4*)(embed + (size_t)gwave * D_);
  float s = 0.f;
#pragma unroll
  for (int i = 0; i < 2; ++i) {
    float4 v = e4[lane + 64 * i];
    s += v.x * v.x + v.y * v.y + v.z * v.z + v.w * v.w;
  }
#pragma unroll
  for (int off = 32; off; off >>= 1) s += __shfl_down(s, off);
  if (lane == 0) ehs[gwave] = 0.5f * s;
}

// -------------------- kernel 2: per-split argmax of (x.e - 0.5*||e||^2) --------------------
// grid: (N/BM, SPLITS), block: 256 threads.
// Thread tile: 8 rows x 8 cols, split as {rg*4..+3, 64+rg*4..+3} x {cg*4..+3, 64+cg*4..+3}
__global__ __launch_bounds__(256, 4) void dist_kernel(const float* __restrict__ x,
                                                      const float* __restrict__ embed,
                                                      const float* __restrict__ ehs,
                                                      float* __restrict__ pbest,
                                                      int* __restrict__ pidx) {
  __shared__ alignas(16) float At[BK][BM];   // x tile, d-major
  __shared__ alignas(16) float Bt[BK][BN];   // embed tile, d-major
  __shared__ float2 red[BM][16];             // (score, idx-bits) per row per col-group

  const int tid = threadIdx.x;
  const int row0 = blockIdx.x * BM;
  const int kbase = blockIdx.y * KSPAN;
  const int rg = tid & 15;
  const int cg = tid >> 4;

  float best[8];
  int bidx[8];
#pragma unroll
  for (int i = 0; i < 8; ++i) { best[i] = -1e30f; bidx[i] = 0; }

  for (int n0 = 0; n0 < KSPAN; n0 += BN) {
    float acc[8][8];
#pragma unroll
    for (int i = 0; i < 8; ++i)
#pragma unroll
      for (int j = 0; j < 8; ++j) acc[i][j] = 0.f;

    for (int d0 = 0; d0 < D_; d0 += BK) {
      // stage: transpose [128 rows][16 d] -> [16 d][128]
#pragma unroll
      for (int i = 0; i < 2; ++i) {
        int idx = tid + 256 * i;        // 0..511
        int rr = idx >> 2, q = idx & 3; // rr: row/col in tile, q: which float4 of the 16 d
        float4 va = *(const float4*)(&x[(size_t)(row0 + rr) * D_ + d0 + q * 4]);
        At[q * 4 + 0][rr] = va.x; At[q * 4 + 1][rr] = va.y;
        At[q * 4 + 2][rr] = va.z; At[q * 4 + 3][rr] = va.w;
        float4 vb = *(const float4*)(&embed[(size_t)(kbase + n0 + rr) * D_ + d0 + q * 4]);
        Bt[q * 4 + 0][rr] = vb.x; Bt[q * 4 + 1][rr] = vb.y;
        Bt[q * 4 + 2][rr] = vb.z; Bt[q * 4 + 3][rr] = vb.w;
      }
      __syncthreads();
#pragma unroll
      for (int kk = 0; kk < BK; ++kk) {
        const float4 a0 = *(const float4*)(&At[kk][rg * 4]);
        const float4 a1 = *(const float4*)(&At[kk][64 + rg * 4]);
        const float4 b0 = *(const float4*)(&Bt[kk][cg * 4]);
        const float4 b1 = *(const float4*)(&Bt[kk][64 + cg * 4]);
        float a[8] = {a0.x, a0.y, a0.z, a0.w, a1.x, a1.y, a1.z, a1.w};
        float b[8] = {b0.x, b0.y, b0.z, b0.w, b1.x, b1.y, b1.z, b1.w};
#pragma unroll
        for (int i = 0; i < 8; ++i)
#pragma unroll
          for (int j = 0; j < 8; ++j) acc[i][j] = fmaf(a[i], b[j], acc[i][j]);
      }
      __syncthreads();
    }

    // argmax update over this 128-col chunk (ascending col order per thread -> strict '>'
    // keeps the first/smallest index among this thread's columns)
#pragma unroll
    for (int jg = 0; jg < 2; ++jg)
#pragma unroll
      for (int j = 0; j < 4; ++j) {
        int col = n0 + jg * 64 + cg * 4 + j;
        float eh = ehs[kbase + col];
#pragma unroll
        for (int i = 0; i < 8; ++i) {
          float s = acc[i][jg * 4 + j] - eh;
          if (s > best[i]) { best[i] = s; bidx[i] = kbase + col; }
        }
      }
  }

  // merge across the 16 col-groups per row (tie -> smaller index, matching np.argmax)
#pragma unroll
  for (int slot = 0; slot < 8; ++slot) {
    int r = (slot >= 4 ? 64 : 0) + rg * 4 + (slot & 3);
    red[r][cg] = make_float2(best[slot], __int_as_float(bidx[slot]));
  }
  __syncthreads();
  if (tid < BM) {
    float b = -1e30f; int bi = 0x7fffffff;
#pragma unroll
    for (int c = 0; c < 16; ++c) {
      float2 v = red[tid][c];
      int id = __float_as_int(v.y);
      if (v.x > b || (v.x == b && id < bi)) { b = v.x; bi = id; }
    }
    pbest[(size_t)blockIdx.y * N_ + row0 + tid] = b;
    pidx[(size_t)blockIdx.y * N_ + row0 + tid] = bi;
  }
}

// -------------------- kernel 3: combine splits + gather embed rows --------------------
__global__ __launch_bounds__(256) void combine_gather(const float* __restrict__ embed,
                                                      const float* __restrict__ pbest,
                                                      const int* __restrict__ pidx,
                                                      float* __restrict__ out) {
  int wid = (blockIdx.x * 256 + threadIdx.x) >> 6;  // one wave per row
  int lane = threadIdx.x & 63;
  if (wid >= N_) return;
  float b = -1e30f; int bi = 0;
#pragma unroll
  for (int s = 0; s < SPLITS; ++s) {
    float v = pbest[(size_t)s * N_ + wid];
    int id = pidx[(size_t)s * N_ + wid];
    if (v > b || (v == b && id < bi)) { b = v; bi = id; }
  }
  const float4* src = (const float4*)(embed + (size_t)bi * D_);
  float4* dst = (float4*)(out + (size_t)wid * D_);
  dst[lane] = src[lane];
  dst[lane + 64] = src[lane + 64];
  if (lane == 0) out[(size_t)N_ * D_ + wid] = (float)bi;  // indices as float32
}

extern "C" void kernel_launch(void* const* d_in, const int* in_sizes, int n_in,
                              void* d_out, int out_size, void* d_ws, size_t ws_size,
                              hipStream_t stream) {
  const float* x = (const float*)d_in[0];       // [16384, 512]
  const float* embed = (const float*)d_in[1];   // [8192, 512]
  float* out = (float*)d_out;                   // [16384*512 quantize][16384 idx-as-f32]

  char* ws = (char*)d_ws;
  float* ehs = (float*)ws;                               // 8192 floats
  float* pbest = (float*)(ws + 32768);                   // SPLITS*16384 floats
  int* pidx = (int*)(ws + 32768 + SPLITS * N_ * 4);      // SPLITS*16384 ints

  ehs_kernel<<<K_ * 64 / 256, 256, 0, stream>>>(embed, ehs);
  dist_kernel<<<dim3(N_ / BM, SPLITS), 256, 0, stream>>>(x, embed, ehs, pbest, pidx);
  combine_gather<<<N_ * 64 / 256, 256, 0, stream>>>(embed, pbest, pidx, out);
}

// Round 2
// 1103.651 us; speedup vs baseline: 1.6136x; 1.6136x over previous
//
#include <hip/hip_runtime.h>
#include <cstddef>
#include <cstdint>

typedef unsigned short ushort_t;
typedef __attribute__((ext_vector_type(8))) short short8;
typedef __attribute__((ext_vector_type(4))) float f32x4;

constexpr int D_ = 512, K_ = 8192, N_ = 16384;   // dims: feature, codebook, rows
constexpr float MARGIN = 0.75f;                   // ~10 sigma of bf16 score noise per side

// RNE float->bf16 (data has no NaN)
__device__ __forceinline__ ushort_t f2bf(float f) {
  unsigned u = __float_as_uint(f);
  return (ushort_t)((u + 0x7FFFu + ((u >> 16) & 1u)) >> 16);
}

__device__ __forceinline__ void gld16(void* l, const void* g) {
  __builtin_amdgcn_global_load_lds((const __attribute__((address_space(1))) void*)g,
                                   (__attribute__((address_space(3))) void*)l, 16, 0, 0);
}

// -------- init: zero fallback state --------
__global__ __launch_bounds__(256) void init_ws(unsigned long long* fbbest, int* fcount) {
  int t = blockIdx.x * 256 + threadIdx.x;
  if (t < N_) fbbest[t] = 0ull;
  if (t == 0) *fcount = 0;
}

// -------- convert x -> bf16 --------
__global__ __launch_bounds__(256) void conv_x(const float* __restrict__ x, ushort_t* __restrict__ xb) {
  int t = blockIdx.x * 256 + threadIdx.x;          // 8 elems per thread
  const float4* p = (const float4*)x;
  float4 a = p[t * 2], b = p[t * 2 + 1];
  short8 v;
  v[0] = (short)f2bf(a.x); v[1] = (short)f2bf(a.y); v[2] = (short)f2bf(a.z); v[3] = (short)f2bf(a.w);
  v[4] = (short)f2bf(b.x); v[5] = (short)f2bf(b.y); v[6] = (short)f2bf(b.z); v[7] = (short)f2bf(b.w);
  *(short8*)(xb + (size_t)t * 8) = v;
}

// -------- convert embed -> bf16, ehs = 0.5*||e||^2 (fp32) --------
__global__ __launch_bounds__(256) void conv_e(const float* __restrict__ e, ushort_t* __restrict__ eb,
                                              float* __restrict__ ehs) {
  int w = (blockIdx.x * 256 + threadIdx.x) >> 6;
  int l = threadIdx.x & 63;
  const float4* p = (const float4*)(e + (size_t)w * D_);
  float4 a = p[l * 2], b = p[l * 2 + 1];
  float s = a.x * a.x + a.y * a.y + a.z * a.z + a.w * a.w
          + b.x * b.x + b.y * b.y + b.z * b.z + b.w * b.w;
  short8 v;
  v[0] = (short)f2bf(a.x); v[1] = (short)f2bf(a.y); v[2] = (short)f2bf(a.z); v[3] = (short)f2bf(a.w);
  v[4] = (short)f2bf(b.x); v[5] = (short)f2bf(b.y); v[6] = (short)f2bf(b.z); v[7] = (short)f2bf(b.w);
  *(short8*)(eb + (size_t)w * D_ + l * 8) = v;
#pragma unroll
  for (int off = 32; off; off >>= 1) s += __shfl_xor(s, off);
  if (l == 0) ehs[w] = 0.5f * s;
}

// -------- MFMA scoring: per-row top-2 per 128-col block --------
// grid (N_/128, K_/128), 256 threads (4 waves, 2x2 wave grid, 64x64 per wave)
__global__ __launch_bounds__(256, 2) void dist_mfma(const ushort_t* __restrict__ xb,
                                                    const ushort_t* __restrict__ eb,
                                                    const float* __restrict__ ehs,
                                                    float4* __restrict__ pp) {
  __shared__ alignas(16) char lds[16384];
  char* As = lds;            // [kq(4)][row(128)] 16B chunks: kq*2048 + r*16
  char* Bs = lds + 8192;
  const int tid = threadIdx.x, w = tid >> 6, l = tid & 63;
  const int row0 = blockIdx.x * 128, col0 = blockIdx.y * 128;
  const int wr = w >> 1, wc = w & 1;

  f32x4 acc[4][4] = {};
  for (int d0 = 0; d0 < D_; d0 += 32) {
#pragma unroll
    for (int i = 0; i < 2; ++i) {
      // wave w stages k-quarter kq=w, rows i*64 + lane. lane's 16B src: row*512 + d0 + w*8 elems
      gld16(As + w * 2048 + i * 1024, xb + (size_t)(row0 + i * 64 + l) * D_ + d0 + w * 8);
      gld16(Bs + w * 2048 + i * 1024, eb + (size_t)(col0 + i * 64 + l) * D_ + d0 + w * 8);
    }
    __syncthreads();
    short8 a[4], b[4];
#pragma unroll
    for (int i = 0; i < 4; ++i)
      a[i] = *(const short8*)(As + (l >> 4) * 2048 + (wr * 64 + i * 16 + (l & 15)) * 16);
#pragma unroll
    for (int j = 0; j < 4; ++j)
      b[j] = *(const short8*)(Bs + (l >> 4) * 2048 + (wc * 64 + j * 16 + (l & 15)) * 16);
#pragma unroll
    for (int i = 0; i < 4; ++i)
#pragma unroll
      for (int j = 0; j < 4; ++j)
        acc[i][j] = __builtin_amdgcn_mfma_f32_16x16x32_bf16(a[i], b[j], acc[i][j], 0, 0, 0);
    __syncthreads();
  }

  // epilogue: score = acc - ehs; per-row top-2 over this block's 128 cols
  int colg[4];
  float eh[4];
#pragma unroll
  for (int j = 0; j < 4; ++j) { colg[j] = col0 + wc * 64 + j * 16 + (l & 15); eh[j] = ehs[colg[j]]; }

  float s1[16], s2[16];
  int i1[16];
#pragma unroll
  for (int i = 0; i < 4; ++i)
#pragma unroll
    for (int r = 0; r < 4; ++r) {
      int s = i * 4 + r;
      s1[s] = -3e38f; s2[s] = -3e38f; i1[s] = 0;
#pragma unroll
      for (int j = 0; j < 4; ++j) {
        float v = acc[i][j][r] - eh[j];
        if (v > s1[s]) { s2[s] = s1[s]; s1[s] = v; i1[s] = colg[j]; }
        else if (v > s2[s]) s2[s] = v;
      }
    }
  // merge across the 16 lanes (low-4 bits) sharing the same row set
#pragma unroll
  for (int m = 1; m < 16; m <<= 1) {
#pragma unroll
    for (int s = 0; s < 16; ++s) {
      float os1 = __shfl_xor(s1[s], m), os2 = __shfl_xor(s2[s], m);
      int oi1 = __shfl_xor(i1[s], m);
      if (os1 > s1[s] || (os1 == s1[s] && oi1 < i1[s])) {
        s2[s] = fmaxf(s1[s], os2); s1[s] = os1; i1[s] = oi1;
      } else {
        s2[s] = fmaxf(s2[s], os1);
      }
    }
  }
  // lane (g = l>>4, c = l&15) owns slot c -> row wr*64 + (c>>2)*16 + g*4 + (c&3)
  const int c = l & 15, g = l >> 4;
  const int rib = wr * 64 + (c >> 2) * 16 + g * 4 + (c & 3);
  float fs1 = s1[c], fs2 = s2[c];
  int fi1 = i1[c];

  // cross-wave (wc) merge via LDS scratch (safe: loop ended on __syncthreads)
  float* ss1 = (float*)lds;
  float* ss2 = ss1 + 128;
  int* si1 = (int*)(ss2 + 128);
  if (wc == 1) { ss1[rib] = fs1; ss2[rib] = fs2; si1[rib] = fi1; }
  __syncthreads();
  if (wc == 0) {
    float os1 = ss1[rib], os2 = ss2[rib];
    int oi1 = si1[rib];
    if (os1 > fs1 || (os1 == fs1 && oi1 < fi1)) { fs2 = fmaxf(fs1, os2); fs1 = os1; fi1 = oi1; }
    else fs2 = fmaxf(fs2, os1);
    pp[(size_t)(row0 + rib) * 64 + blockIdx.y] = make_float4(fs1, __int_as_float(fi1), fs2, 0.f);
  }
}

// -------- combine 64 partials/row; emit output or flag for exact rescore --------
__global__ __launch_bounds__(256) void combine(const float4* __restrict__ pp,
                                               const float* __restrict__ embed,
                                               float* __restrict__ out,
                                               int* __restrict__ flagged, int* __restrict__ fcount) {
  int row = (blockIdx.x * 256 + threadIdx.x) >> 6;
  int l = threadIdx.x & 63;
  float4 v = pp[(size_t)row * 64 + l];
  float s1 = v.x, s2 = v.z;
  int i1 = __float_as_int(v.y);
#pragma unroll
  for (int m = 1; m < 64; m <<= 1) {
    float os1 = __shfl_xor(s1, m), os2 = __shfl_xor(s2, m);
    int oi1 = __shfl_xor(i1, m);
    if (os1 > s1 || (os1 == s1 && oi1 < i1)) { s2 = fmaxf(s1, os2); s1 = os1; i1 = oi1; }
    else s2 = fmaxf(s2, os1);
  }
  if (s1 - s2 > MARGIN) {
    const float4* src = (const float4*)(embed + (size_t)i1 * D_);
    float4* dst = (float4*)(out + (size_t)row * D_);
    dst[l] = src[l];
    dst[l + 64] = src[l + 64];
    if (l == 0) out[(size_t)N_ * D_ + row] = (float)i1;
  } else if (l == 0) {
    int slot = atomicAdd(fcount, 1);
    flagged[slot] = row;
  }
}

// -------- exact fp32 rescore of flagged rows: 16 rows x 1024 cols per block --------
__global__ __launch_bounds__(256, 2) void fb_dist(const float* __restrict__ x,
                                                  const float* __restrict__ embed,
                                                  const float* __restrict__ ehs,
                                                  const int* __restrict__ flagged,
                                                  const int* __restrict__ fcount,
                                                  unsigned long long* __restrict__ fbbest) {
  int count = *fcount;
  int tiles = (count + 15) >> 4;
  if ((int)blockIdx.x >= tiles) return;
  __shared__ float xs[16][512];
  __shared__ unsigned long long red[16][4];
  const int tid = threadIdx.x;
  // stage 16 x-rows (fp32) into LDS
  for (int k = 0; k < 8; ++k) {
    int q = tid + 256 * k;
    int r = q >> 7, dq = q & 127;
    int slot = blockIdx.x * 16 + r;
    if (slot >= count) slot = count - 1;
    int row = flagged[slot];
    ((float4*)xs[r])[dq] = ((const float4*)(x + (size_t)row * D_))[dq];
  }
  __syncthreads();

  const int c0 = blockIdx.y * 1024;
  int cols[4];
#pragma unroll
  for (int kk = 0; kk < 4; ++kk) cols[kk] = c0 + tid + 256 * kk;

  float acc[16][4];
#pragma unroll
  for (int r = 0; r < 16; ++r)
#pragma unroll
    for (int kk = 0; kk < 4; ++kk) acc[r][kk] = 0.f;

  for (int d = 0; d < D_; d += 4) {
    float4 ev[4];
#pragma unroll
    for (int kk = 0; kk < 4; ++kk) ev[kk] = *(const float4*)(embed + (size_t)cols[kk] * D_ + d);
#pragma unroll
    for (int r = 0; r < 16; ++r) {
      float4 xv = *(const float4*)(&xs[r][d]);
#pragma unroll
      for (int kk = 0; kk < 4; ++kk) {
        acc[r][kk] = fmaf(ev[kk].x, xv.x, acc[r][kk]);
        acc[r][kk] = fmaf(ev[kk].y, xv.y, acc[r][kk]);
        acc[r][kk] = fmaf(ev[kk].z, xv.z, acc[r][kk]);
        acc[r][kk] = fmaf(ev[kk].w, xv.w, acc[r][kk]);
      }
    }
  }

#pragma unroll
  for (int r = 0; r < 16; ++r) {
    float b = -3e38f;
    int bi = 0;
#pragma unroll
    for (int kk = 0; kk < 4; ++kk) {
      float s = acc[r][kk] - ehs[cols[kk]];
      if (s > b) { b = s; bi = cols[kk]; }   // cols ascending in kk -> strict > keeps min idx
    }
    unsigned ub = __float_as_uint(b);
    unsigned mb = (ub & 0x80000000u) ? ~ub : (ub | 0x80000000u);
    unsigned long long packed = ((unsigned long long)mb << 32) | (0xFFFFFFFFu - (unsigned)bi);
#pragma unroll
    for (int m = 1; m < 64; m <<= 1) {
      unsigned long long o = __shfl_xor(packed, m);
      packed = packed > o ? packed : o;
    }
    if ((tid & 63) == 0) red[r][tid >> 6] = packed;
  }
  __syncthreads();
  if (tid < 16) {
    unsigned long long p0 = red[tid][0] > red[tid][1] ? red[tid][0] : red[tid][1];
    unsigned long long p1 = red[tid][2] > red[tid][3] ? red[tid][2] : red[tid][3];
    unsigned long long p = p0 > p1 ? p0 : p1;
    int slot = blockIdx.x * 16 + tid;
    if (slot < count) atomicMax(&fbbest[flagged[slot]], p);
  }
}

// -------- write outputs for flagged rows --------
__global__ __launch_bounds__(256) void fb_final(const float* __restrict__ embed,
                                                const int* __restrict__ flagged,
                                                const int* __restrict__ fcount,
                                                const unsigned long long* __restrict__ fbbest,
                                                float* __restrict__ out) {
  int count = *fcount;
  int slot = (blockIdx.x * 256 + threadIdx.x) >> 6;
  int l = threadIdx.x & 63;
  if (slot >= count) return;
  int row = flagged[slot];
  unsigned long long p = fbbest[row];
  int idx = (int)(0xFFFFFFFFu - (unsigned)(p & 0xFFFFFFFFu));
  const float4* src = (const float4*)(embed + (size_t)idx * D_);
  float4* dst = (float4*)(out + (size_t)row * D_);
  dst[l] = src[l];
  dst[l + 64] = src[l + 64];
  if (l == 0) out[(size_t)N_ * D_ + row] = (float)idx;
}

extern "C" void kernel_launch(void* const* d_in, const int* in_sizes, int n_in,
                              void* d_out, int out_size, void* d_ws, size_t ws_size,
                              hipStream_t stream) {
  const float* x = (const float*)d_in[0];     // [16384, 512]
  const float* e = (const float*)d_in[1];     // [8192, 512]
  float* out = (float*)d_out;

  char* ws = (char*)d_ws;
  ushort_t* xb = (ushort_t*)ws;                                     // 16 MB
  ushort_t* eb = (ushort_t*)(ws + 16777216);                        // 8 MB
  float* ehs = (float*)(ws + 25165824);                             // 32 KB
  float4* pp = (float4*)(ws + 25198592);                            // 16 MB
  unsigned long long* fbbest = (unsigned long long*)(ws + 41975808);// 128 KB
  int* flagged = (int*)(ws + 42106880);                             // 64 KB
  int* fcount = (int*)(ws + 42172416);                              // 4 B

  init_ws<<<64, 256, 0, stream>>>(fbbest, fcount);
  conv_x<<<4096, 256, 0, stream>>>(x, xb);
  conv_e<<<2048, 256, 0, stream>>>(e, eb, ehs);
  dist_mfma<<<dim3(128, 64), 256, 0, stream>>>(xb, eb, ehs, pp);
  combine<<<4096, 256, 0, stream>>>(pp, e, out, flagged, fcount);
  fb_dist<<<dim3(1024, 8), 256, 0, stream>>>(x, e, ehs, flagged, fcount, fbbest);
  fb_final<<<4096, 256, 0, stream>>>(e, flagged, fcount, fbbest, out);
}